// Round 18
// baseline (422.043 us; speedup 1.0000x reference)
//
#include <hip/hip_runtime.h>
#include <math.h>

#define NN 10000
#define NE 160000
#define M32 32           // edges per message block (16 thr/edge, 2 feats/thr)
#define MT2 512          // message block threads
#define CEPB 16          // edges per coef block
#define DNB 4            // nodes per dense block (processed as pairs)

typedef float float2v __attribute__((ext_vector_type(2)));

namespace {
// MP_PATHS in reference order
constexpr int kL1[11] = {0,0,0,1,1,1,1,2,2,2,2};
constexpr int kL2[11] = {0,1,2,0,1,1,2,0,1,2,2};
constexpr int kL3[11] = {0,1,2,1,0,2,1,2,1,0,2};
// ((l1*3+l2)*3+l3) per path (W slab index)
constexpr int kWOFF[11] = {0,5,7,10,12,14,16,20,22,24,26};
// TD_PATHS in reference order
constexpr int tL1[7] = {0,0,1,1,1,2,2};
constexpr int tL2[7] = {0,1,0,1,2,1,2};
constexpr int tL3[7] = {0,1,1,0,1,1,0};
constexpr int kOFF[3] = {0,1,4};
constexpr int kWID[3] = {1,3,5};

// compile-time (t,i) -> tv-slot tables and c -> (r, tv-slot) tables (fallback kernel)
struct TVT { unsigned char t[35], p[35]; };
constexpr TVT makeTV() {
  TVT v{};
  int ti = 0;
  for (int t = 0; t < 11; ++t)
    for (int i = 0; i < kWID[kL1[t]]; ++i) {
      v.t[ti] = (unsigned char)t;
      v.p[ti] = (unsigned char)(kOFF[kL1[t]] + i);
      ++ti;
    }
  return v;
}
constexpr TVT TV = makeTV();

struct CTb { unsigned char r[116], tv[116]; };
constexpr CTb makeCT() {
  CTb v{};
  int c = 0, ti = 0;
  for (int t = 0; t < 11; ++t)
    for (int i = 0; i < kWID[kL1[t]]; ++i) {
      for (int k = 0; k < kWID[kL3[t]]; ++k) {
        v.r[c]  = (unsigned char)(kOFF[kL3[t]] + k);
        v.tv[c] = (unsigned char)ti;
        ++c;
      }
      ++ti;
    }
  v.r[115] = 0; v.tv[115] = 0;
  return v;
}
constexpr CTb CTC = makeCT();
}

__device__ float GAUNT_d[729];
__device__ unsigned char CT_P_d[115], CT_R_d[115], CT_L2_d[115];

// float32 spherical harmonics component (matches reference _sph_harm numerics)
__device__ __forceinline__ float sphf(int c, float x, float y, float z) {
  const float s3 = 1.7320508075688772f;
  switch (c) {
    case 0: return 1.0f;
    case 1: return x;
    case 2: return y;
    case 3: return z;
    case 4: return s3 * x * y;
    case 5: return s3 * y * z;
    case 6: return 0.5f * (3.0f * z * z - 1.0f);
    case 7: return s3 * x * z;
    default: return 0.5f * s3 * (x * x - y * y);
  }
}

// Gaunt table build: 16 double-trig calls total (staged in LDS), then a
// shared 128pt x 9comp Y table, then 729 threads do pure FMA loops.
__global__ void gaunt_kernel() {
  __shared__ float Ysh[128][9];
  __shared__ double cph[16], sph[16];
  __shared__ double stq[8], tsh[8], wsh[8];
  const int idx = threadIdx.x;
  const double T[8] = {-0.9602898564975363, -0.7966664774136267, -0.5255324099163290, -0.1834346424956498,
                        0.1834346424956498,  0.5255324099163290,  0.7966664774136267,  0.9602898564975363};
  const double Wq[8] = {0.1012285362903763, 0.2223810344533745, 0.3137066458778873, 0.3626837833783620,
                        0.3626837833783620, 0.3137066458778873, 0.2223810344533745, 0.1012285362903763};
  if (idx < 16) {
    double phi = (double)idx * (6.283185307179586 / 16.0);
    cph[idx] = cos(phi);
    sph[idx] = sin(phi);
  }
  if (idx < 8) {
    tsh[idx] = T[idx];
    wsh[idx] = Wq[idx] / 32.0;
    stq[idx] = sqrt(1.0 - T[idx] * T[idx]);
  }
  __syncthreads();
  for (int i = idx; i < 128 * 9; i += 768) {
    int k = i / 9, c = i - k * 9;
    int it = k >> 4, ip = k & 15;
    float xf = (float)(stq[it] * cph[ip]);
    float yf = (float)(stq[it] * sph[ip]);
    float zf = (float)tsh[it];
    Ysh[k][c] = sphf(c, xf, yf, zf);
  }
  __syncthreads();
  if (idx < 729) {
    int p = idx / 81, q = (idx / 9) % 9, r = idx % 9;
    double acc = 0.0;
    for (int k = 0; k < 128; ++k)  // same summation order as reference (it outer, ip inner)
      acc += wsh[k >> 4] * (double)Ysh[k][p] * (double)Ysh[k][q] * (double)Ysh[k][r];
    GAUNT_d[idx] = (fabs(acc) < 1e-10) ? 0.0f : (float)acc;
  }
  if (idx == 0) {
    // coef index -> (p_global, r_global, l2) tables, in (path, i, k) nesting order
    int c = 0;
    for (int t = 0; t < 11; ++t) {
      int l1 = kL1[t], l2 = kL2[t], l3 = kL3[t];
      for (int i = 0; i < kWID[l1]; ++i)
        for (int k = 0; k < kWID[l3]; ++k) {
          CT_P_d[c]  = (unsigned char)(kOFF[l1] + i);
          CT_R_d[c]  = (unsigned char)(kOFF[l3] + k);
          CT_L2_d[c] = (unsigned char)l2;
          ++c;
        }
    }
  }
}

// ---- destination-sorted edge order build ----
__global__ void hist_kernel(const int* __restrict__ dstI, int* __restrict__ cnt) {
  int e = blockIdx.x * 256 + threadIdx.x;
  if (e < NE) atomicAdd(&cnt[dstI[e]], 1);
}

// single-block in-place exclusive scan over wofs (counts -> start offsets)
__global__ void scan_kernel(int* __restrict__ wofs) {
  __shared__ int partial[1024];
  const int tid = threadIdx.x;           // 1024 threads, 10 elements each
  const int base = tid * 10;
  int local[10];
  int s = 0;
  #pragma unroll
  for (int i = 0; i < 10; ++i) {
    int idx = base + i;
    int v = (idx < NN) ? wofs[idx] : 0;
    local[i] = s;                        // exclusive within chunk
    s += v;
  }
  partial[tid] = s;
  __syncthreads();
  for (int off = 1; off < 1024; off <<= 1) {
    int v = (tid >= off) ? partial[tid - off] : 0;
    __syncthreads();
    partial[tid] += v;
    __syncthreads();
  }
  int pre = (tid == 0) ? 0 : partial[tid - 1];
  #pragma unroll
  for (int i = 0; i < 10; ++i) {
    int idx = base + i;
    if (idx < NN) wofs[idx] = pre + local[i];
  }
}

// edge basis, scattered directly into dst-sorted slot order
__global__ void edge_kernel(const float* __restrict__ pos,
                            const int* __restrict__ srcI, const int* __restrict__ dstI,
                            int* __restrict__ wofs, int* __restrict__ ssrc, int* __restrict__ sdst,
                            float* __restrict__ Yb, float* __restrict__ Rb) {
  int e = blockIdx.x * 256 + threadIdx.x;
  if (e >= NE) return;
  int s = srcI[e], d = dstI[e];
  float dx = pos[s * 3 + 0] - pos[d * 3 + 0];
  float dy = pos[s * 3 + 1] - pos[d * 3 + 1];
  float dz = pos[s * 3 + 2] - pos[d * 3 + 2];
  float r2 = dx * dx + dy * dy + dz * dz;
  float r = sqrtf(fmaxf(r2, 1e-12f));
  float inv = 1.0f / r;
  float x = dx * inv, y = dy * inv, z = dz * inv;
  const float s3 = 1.7320508075688772f;
  int sp = atomicAdd(&wofs[d], 1);       // dst-sorted slot
  ssrc[sp] = s;
  sdst[sp] = d;
  Yb[sp * 9 + 0] = 1.0f;
  Yb[sp * 9 + 1] = x;
  Yb[sp * 9 + 2] = y;
  Yb[sp * 9 + 3] = z;
  Yb[sp * 9 + 4] = s3 * x * y;
  Yb[sp * 9 + 5] = s3 * y * z;
  Yb[sp * 9 + 6] = 0.5f * (3.0f * z * z - 1.0f);
  Yb[sp * 9 + 7] = s3 * x * z;
  Yb[sp * 9 + 8] = 0.5f * s3 * (x * x - y * y);
  float rc = fminf(r, 5.0f - 1e-6f);
  float cut = (r < 5.0f) ? expf(-(rc * rc) / ((5.0f - rc) * (5.0f + rc))) : 0.0f;
  float yv = 1.0f / (1.0f + r);
  float om = 1.0f - yv;
  const float binom[8] = {1.f, 7.f, 21.f, 35.f, 35.f, 21.f, 7.f, 1.f};
  float yk[8], ok[8];
  yk[0] = 1.0f; ok[0] = 1.0f;
  #pragma unroll
  for (int k = 1; k < 8; ++k) { yk[k] = yk[k - 1] * yv; ok[k] = ok[k - 1] * om; }
  #pragma unroll
  for (int k = 0; k < 8; ++k) Rb[sp * 8 + k] = binom[k] * yk[k] * ok[7 - k] * cut;
}

// per-edge Gaunt-contracted coefficients, computed ONCE (iteration-independent):
// Cb[e][c] = sum_q G[p(c), q, r(c)] * Y[e][q], padded to 116 floats/row
__global__ void coef_kernel(const float* __restrict__ Yb, float* __restrict__ Cb) {
  __shared__ float Gs[729];
  __shared__ float Ys[CEPB][9];
  __shared__ unsigned char Tp[115], Tr[115], Tl2[115];
  const int tid = threadIdx.x;
  const int e0 = blockIdx.x * CEPB;
  for (int i = tid; i < 729; i += 256) Gs[i] = GAUNT_d[i];
  for (int i = tid; i < 115; i += 256) { Tp[i] = CT_P_d[i]; Tr[i] = CT_R_d[i]; Tl2[i] = CT_L2_d[i]; }
  for (int i = tid; i < CEPB * 9; i += 256) Ys[i / 9][i % 9] = Yb[e0 * 9 + i];
  __syncthreads();
  for (int i = tid; i < CEPB * 128; i += 256) {
    int ce = i >> 7, c = i & 127;
    if (c < 116) {
      float a = 0.0f;
      if (c < 115) {
        int p = Tp[c], r = Tr[c], l2 = Tl2[c];
        int q0 = (l2 == 0) ? 0 : ((l2 == 1) ? 1 : 4);
        int nq = (l2 == 0) ? 1 : ((l2 == 1) ? 3 : 5);
        for (int j = 0; j < nq; ++j) a += Gs[(p * 9 + q0 + j) * 9 + r] * Ys[ce][q0 + j];
      }
      Cb[(size_t)(e0 + ce) * 116 + c] = a;
    }
  }
}

// x init + y zero
__global__ void init_kernel(const float* __restrict__ embed, const int* __restrict__ Z,
                            float* __restrict__ xb, float* __restrict__ yb) {
  int idx = blockIdx.x * 256 + threadIdx.x;
  if (idx >= NN * 288) return;
  int n = idx / 288;
  int rem = idx - n * 288;
  int p = rem >> 5, f = rem & 31;
  xb[idx] = (p == 0) ? embed[Z[n] * 32 + f] : 0.0f;
  yb[idx] = 0.0f;
}

// edge-major message pass, packed-FP32 form: 16 threads/edge x 2 features/thread,
// 32 edges per 512-thread block (halves per-block W staging and fixed latency
// vs 16-edge blocks at the same 32-wave/CU occupancy). Ws/Ms share one LDS
// array; Ms reduction runs in four 8-edge sub-batches (seg-outer loop, no idiv).
__launch_bounds__(MT2, 8)
__global__ void message_kernel(const float* __restrict__ xb, float* __restrict__ yb,
                               const float* __restrict__ Rb, const float* __restrict__ Cb,
                               const float* __restrict__ Wg,
                               const int* __restrict__ ssrc, const int* __restrict__ sdst) {
  __shared__ __align__(16) float U[11 * 256];    // phase A: Ws[t][k*32+f]; phase B: Ms[8][288]
  __shared__ __align__(16) float Cs[M32][116];
  __shared__ __align__(16) float Rs[M32][8];
  __shared__ int Ds[M32];
  __shared__ int Hs[4][9];
  __shared__ int nsegS[4];
  const int tid = threadIdx.x;
  const int e0 = blockIdx.x * M32;
  const int le = tid >> 4;          // edge slot 0..31
  const int f  = (tid & 15) * 2;    // even feature index; thread owns f, f+1

  // issue the x[src] gather FIRST (no LDS dependency); latency hides under staging
  const int sn = ssrc[e0 + le];
  float2v xs2[9];
  #pragma unroll
  for (int p = 0; p < 9; ++p) xs2[p] = *(const float2v*)&xb[sn * 288 + p * 32 + f];

  float* Ws = U;
  #pragma unroll
  for (int i = tid; i < 11 * 256; i += MT2) {
    int t = i >> 8, s = i & 255;
    Ws[t * 256 + s] = Wg[kWOFF[t] * 256 + s];
  }
  {
    const float4* Cbv = (const float4*)Cb;
    float4* Csv = (float4*)Cs;
    #pragma unroll
    for (int i = tid; i < M32 * 29; i += MT2) Csv[i] = Cbv[(size_t)e0 * 29 + i];
  }
  for (int i = tid; i < M32 * 8; i += MT2) Rs[i >> 3][i & 7] = Rb[e0 * 8 + i];
  if (tid < M32) Ds[tid] = sdst[e0 + tid];
  __syncthreads();

  if (tid == 0) {
    // segment heads among the sorted edges, per 8-edge sub-batch
    #pragma unroll
    for (int b = 0; b < 4; ++b) {
      int ns = 0;
      #pragma unroll
      for (int i = 0; i < 8; ++i) {
        int gi = b * 8 + i;
        if (i == 0 || Ds[gi] != Ds[gi - 1]) Hs[b][ns++] = i;
      }
      Hs[b][ns] = 8;
      nsegS[b] = ns;
    }
  }

  // core math, packed over (f, f+1): per path t compute rw (8 pk-FMA), then
  // the (i,k) message terms; same summation order as the reference loop.
  float2v msg[9] = {{0.f,0.f},{0.f,0.f},{0.f,0.f},{0.f,0.f},{0.f,0.f},{0.f,0.f},{0.f,0.f},{0.f,0.f},{0.f,0.f}};
  int c = 0;
  #pragma unroll
  for (int t = 0; t < 11; ++t) {
    const float* base = &Ws[t * 256];
    float2v acc = {0.f, 0.f};
    #pragma unroll
    for (int k = 0; k < 8; ++k) {
      const float rv = Rs[le][k];
      const float2v rvv = {rv, rv};
      const float2v w2 = *(const float2v*)&base[k * 32 + f];
      acc = acc + rvv * w2;
    }
    const int o1 = kOFF[kL1[t]], w1 = kWID[kL1[t]];
    const int o3 = kOFF[kL3[t]], w3 = kWID[kL3[t]];
    #pragma unroll
    for (int i = 0; i < w1; ++i) {
      const float2v tvv = acc * xs2[o1 + i];
      #pragma unroll
      for (int k2 = 0; k2 < w3; ++k2) {
        const float cc = Cs[le][c]; ++c;
        const float2v ccv = {cc, cc};
        msg[o3 + k2] = msg[o3 + k2] + ccv * tvv;
      }
    }
  }

  // four sub-batch segmented reductions reusing U as Ms[8][288]
  float* Ms = U;
  #pragma unroll
  for (int b = 0; b < 4; ++b) {
    __syncthreads();                  // b=0: all Ws reads done; b>0: prior batch reads done
    if ((le >> 3) == b) {
      #pragma unroll
      for (int rr = 0; rr < 9; ++rr)
        *(float2v*)&Ms[(le & 7) * 288 + rr * 32 + f] = msg[rr];
    }
    __syncthreads();
    const int ns = nsegS[b];
    for (int s = 0; s < ns; ++s) {    // segment-outer loop: no integer division
      const int h = Hs[b][s], hend = Hs[b][s + 1];
      const int dbase = Ds[b * 8 + h] * 288;
      for (int rf = tid; rf < 288; rf += MT2) {
        float a = 0.0f;
        for (int e = h; e < hend; ++e) a += Ms[e * 288 + rf];
        atomicAdd(&yb[dbase + rf], a);
      }
    }
  }
}

// iteration-0 message pass: x is zero except the p=0 (embedding) row, so only
// the 3 MP paths with l1=0 contribute (exact zeros elsewhere). 1 x-row gather,
// 3 W slabs, 9 C coefficients; reduction phase identical to message_kernel.
__launch_bounds__(MT2, 8)
__global__ void message0_kernel(const float* __restrict__ xb, float* __restrict__ yb,
                                const float* __restrict__ Rb, const float* __restrict__ Cb,
                                const float* __restrict__ Wg,
                                const int* __restrict__ ssrc, const int* __restrict__ sdst) {
  __shared__ __align__(16) float U[8 * 288];     // phase A: Ws[3][256] (first 768); phase B: Ms[8][288]
  __shared__ __align__(16) float Cs[M32][12];
  __shared__ __align__(16) float Rs[M32][8];
  __shared__ int Ds[M32];
  __shared__ int Hs[4][9];
  __shared__ int nsegS[4];
  const int tid = threadIdx.x;
  const int e0 = blockIdx.x * M32;
  const int le = tid >> 4;          // edge slot 0..31
  const int f  = (tid & 15) * 2;    // even feature index; thread owns f, f+1

  const int sn = ssrc[e0 + le];
  const float2v xs0 = *(const float2v*)&xb[sn * 288 + f];   // p=0 row only

  float* Ws = U;
  if (tid < 3 * 256) {
    int t = tid >> 8, s = tid & 255;
    Ws[t * 256 + s] = Wg[kWOFF[t] * 256 + s];   // kWOFF[0..2] = 0,5,7
  }
  if (tid < M32 * 3) {               // 96 float4: first 12 coefs of each edge row
    const float4* Cbv = (const float4*)Cb;
    int row = tid / 3, c4 = tid - row * 3;
    ((float4*)Cs)[row * 3 + c4] = Cbv[(size_t)(e0 + row) * 29 + c4];
  }
  for (int i = tid; i < M32 * 8; i += MT2) Rs[i >> 3][i & 7] = Rb[e0 * 8 + i];
  if (tid < M32) Ds[tid] = sdst[e0 + tid];
  __syncthreads();

  if (tid == 0) {
    #pragma unroll
    for (int b = 0; b < 4; ++b) {
      int ns = 0;
      #pragma unroll
      for (int i = 0; i < 8; ++i) {
        int gi = b * 8 + i;
        if (i == 0 || Ds[gi] != Ds[gi - 1]) Hs[b][ns++] = i;
      }
      Hs[b][ns] = 8;
      nsegS[b] = ns;
    }
  }

  // rw for the 3 surviving paths, then the 9 message terms
  float2v msg[9];
  {
    float2v acc[3];
    #pragma unroll
    for (int t = 0; t < 3; ++t) {
      const float* base = &Ws[t * 256];
      float2v a = {0.f, 0.f};
      #pragma unroll
      for (int k = 0; k < 8; ++k) {
        const float rv = Rs[le][k];
        const float2v rvv = {rv, rv};
        const float2v w2 = *(const float2v*)&base[k * 32 + f];
        a = a + rvv * w2;
      }
      acc[t] = a;
    }
    const float2v tv0 = acc[0] * xs0;   // path (0,0,0) -> r=0,   c=0
    const float2v tv1 = acc[1] * xs0;   // path (0,1,1) -> r=1..3, c=1..3
    const float2v tv2 = acc[2] * xs0;   // path (0,2,2) -> r=4..8, c=4..8
    msg[0] = (float2v){Cs[le][0], Cs[le][0]} * tv0;
    #pragma unroll
    for (int k = 0; k < 3; ++k) {
      const float cc = Cs[le][1 + k];
      msg[1 + k] = (float2v){cc, cc} * tv1;
    }
    #pragma unroll
    for (int k = 0; k < 5; ++k) {
      const float cc = Cs[le][4 + k];
      msg[4 + k] = (float2v){cc, cc} * tv2;
    }
  }

  // four sub-batch segmented reductions reusing U as Ms[8][288]
  float* Ms = U;
  #pragma unroll
  for (int b = 0; b < 4; ++b) {
    __syncthreads();
    if ((le >> 3) == b) {
      #pragma unroll
      for (int rr = 0; rr < 9; ++rr)
        *(float2v*)&Ms[(le & 7) * 288 + rr * 32 + f] = msg[rr];
    }
    __syncthreads();
    const int ns = nsegS[b];
    for (int s = 0; s < ns; ++s) {
      const int h = Hs[b][s], hend = Hs[b][s + 1];
      const int dbase = Ds[b * 8 + h] * 288;
      for (int rf = tid; rf < 288; rf += MT2) {
        float a = 0.0f;
        for (int e = h; e < hend; ++e) a += Ms[e * 288 + rf];
        atomicAdd(&yb[dbase + rf], a);
      }
    }
  }
}

// fallback (in-kernel coef, round-3 form, 8 edges/block) if workspace too small for Cb
__launch_bounds__(256)
__global__ void message_kernel_ic(const float* __restrict__ xb, float* __restrict__ yb,
                                  const float* __restrict__ Yb, const float* __restrict__ Rb,
                                  const float* __restrict__ Wg,
                                  const int* __restrict__ ssrc, const int* __restrict__ sdst) {
  __shared__ float Gs[729];
  __shared__ float Ws[11 * 256];
  __shared__ float Ys[8][9];
  __shared__ float Rs[8][8];
  __shared__ float Cs[8][116];
  __shared__ float Ms[8][288];
  __shared__ int Ds[8];
  __shared__ int Hs[9];
  __shared__ int nseg_s;
  __shared__ unsigned char Tp[115], Tr[115], Tl2[115];
  const int tid = threadIdx.x;
  const int e0 = blockIdx.x * 8;

  for (int i = tid; i < 729; i += 256) Gs[i] = GAUNT_d[i];
  for (int i = tid; i < 115; i += 256) { Tp[i] = CT_P_d[i]; Tr[i] = CT_R_d[i]; Tl2[i] = CT_L2_d[i]; }
  #pragma unroll
  for (int t = 0; t < 11; ++t) Ws[t * 256 + tid] = Wg[kWOFF[t] * 256 + tid];
  for (int i = tid; i < 8 * 16; i += 256) {
    int le = i >> 4, q = i & 15;
    if (q < 9) Ys[le][q] = Yb[(e0 + le) * 9 + q];
  }
  for (int i = tid; i < 8 * 8; i += 256) Rs[i >> 3][i & 7] = Rb[e0 * 8 + i];
  if (tid < 8) Ds[tid] = sdst[e0 + tid];
  __syncthreads();

  const int le = tid >> 5, f = tid & 31;
  const int sn = ssrc[e0 + le];
  float xs[9];
  #pragma unroll
  for (int p = 0; p < 9; ++p) xs[p] = xb[sn * 288 + p * 32 + f];

  for (int i = tid; i < 8 * 128; i += 256) {
    int ce = i >> 7, c = i & 127;
    if (c < 115) {
      int p = Tp[c], r = Tr[c], l2 = Tl2[c];
      int q0 = (l2 == 0) ? 0 : ((l2 == 1) ? 1 : 4);
      int nq = (l2 == 0) ? 1 : ((l2 == 1) ? 3 : 5);
      float a = 0.0f;
      for (int j = 0; j < nq; ++j) a += Gs[(p * 9 + q0 + j) * 9 + r] * Ys[ce][q0 + j];
      Cs[ce][c] = a;
    }
  }
  if (tid == 0) {
    int ns = 0;
    #pragma unroll
    for (int i = 0; i < 8; ++i)
      if (i == 0 || Ds[i] != Ds[i - 1]) Hs[ns++] = i;
    Hs[ns] = 8;
    nseg_s = ns;
  }
  __syncthreads();

  const float4 R0 = *(const float4*)&Rs[le][0];
  const float4 R1 = *(const float4*)&Rs[le][4];
  float rw[11];
  #pragma unroll
  for (int t = 0; t < 11; ++t) {
    const float* base = &Ws[t * 256];
    rw[t] = R0.x * base[f] + R0.y * base[32 + f] + R0.z * base[64 + f] + R0.w * base[96 + f]
          + R1.x * base[128 + f] + R1.y * base[160 + f] + R1.z * base[192 + f] + R1.w * base[224 + f];
  }
  float tv[35];
  #pragma unroll
  for (int j = 0; j < 35; ++j) tv[j] = rw[TV.t[j]] * xs[TV.p[j]];
  float msg[9] = {0.f, 0.f, 0.f, 0.f, 0.f, 0.f, 0.f, 0.f, 0.f};
  #pragma unroll
  for (int c = 0; c < 115; ++c) msg[CTC.r[c]] += Cs[le][c] * tv[CTC.tv[c]];
  #pragma unroll
  for (int rr = 0; rr < 9; ++rr) Ms[le][rr * 32 + f] = msg[rr];
  __syncthreads();

  const int nseg = nseg_s;
  for (int i = tid; i < nseg * 288; i += 256) {
    int s = i / 288, rf = i - s * 288;
    int h = Hs[s], hend = Hs[s + 1];
    float a = 0.0f;
    for (int e = h; e < hend; ++e) a += Ms[e][rf];
    atomicAdd(&yb[Ds[h] * 288 + rf], a);
  }
}

// fused dense1 + silu_e3 + dense2 + residual; DNB nodes per block as pairs.
// W read straight from global: W1/W2 are identical for all blocks, so one L1
// copy per CU serves every resident block.
__launch_bounds__(288)
__global__ void dense_kernel(float* __restrict__ ybuf, float* __restrict__ xb,
                             const float* __restrict__ W1, const float* __restrict__ b1,
                             const float* __restrict__ W2, const float* __restrict__ b2) {
  __shared__ float yn0[288], yn1[288];
  __shared__ float act0[288], act1[288];
  __shared__ float sb0[32], sb1[32];
  const int tid = threadIdx.x;  // p*32+g
  const int p = tid >> 5, g = tid & 31;
  const int dg = (p == 0) ? 0 : ((p < 4) ? 1 : 2);
  const float b1v = b1[g], b2v = b2[g];
  const float* W1d = W1 + dg * 1024 + g;   // W1[(dg*32+f)*32+g] = W1d[f*32]
  const float* W2d = W2 + dg * 1024 + g;
  const int n0 = blockIdx.x * DNB;
  float xv0 = xb[n0 * 288 + tid];
  float yv0 = ybuf[n0 * 288 + tid];
  float xv1 = xb[(n0 + 1) * 288 + tid];
  float yv1 = ybuf[(n0 + 1) * 288 + tid];
  for (int n = n0; n < n0 + DNB; n += 2) {
    yn0[tid] = xv0 + yv0;
    yn1[tid] = xv1 + yv1;
    ybuf[n * 288 + tid] = 0.0f;        // zero for next iteration's atomics
    ybuf[(n + 1) * 288 + tid] = 0.0f;
    __syncthreads();
    float xva = 0.0f, yva = 0.0f, xvb = 0.0f, yvb = 0.0f;
    if (n + 2 < n0 + DNB) {            // prefetch next pair under compute
      xva = xb[(n + 2) * 288 + tid];
      yva = ybuf[(n + 2) * 288 + tid];
      xvb = xb[(n + 3) * 288 + tid];
      yvb = ybuf[(n + 3) * 288 + tid];
    }
    float a0 = (p == 0) ? b1v : 0.0f;
    float a1 = (p == 0) ? b1v : 0.0f;
    #pragma unroll
    for (int f = 0; f < 32; ++f) {
      const float w = W1d[f * 32];
      a0 += yn0[p * 32 + f] * w;
      a1 += yn1[p * 32 + f] * w;
    }
    if (p == 0) { sb0[g] = a0; sb1[g] = a1; }
    __syncthreads();
    const float s0 = sb0[g], s1 = sb1[g];
    const float sg0 = 1.0f / (1.0f + expf(-s0));
    const float sg1 = 1.0f / (1.0f + expf(-s1));
    const float v0 = (p == 0) ? s0 * sg0 : a0 * (sg0 * (1.0f + s0 * (1.0f - sg0)));
    const float v1 = (p == 0) ? s1 * sg1 : a1 * (sg1 * (1.0f + s1 * (1.0f - sg1)));
    act0[tid] = v0;
    act1[tid] = v1;
    __syncthreads();
    float o0 = (p == 0) ? b2v : 0.0f;
    float o1 = (p == 0) ? b2v : 0.0f;
    #pragma unroll
    for (int f = 0; f < 32; ++f) {
      const float w = W2d[f * 32];
      o0 += act0[p * 32 + f] * w;
      o1 += act1[p * 32 + f] * w;
    }
    xb[n * 288 + tid] = xv0 + o0;
    xb[(n + 1) * 288 + tid] = xv1 + o1;
    __syncthreads();                   // yn/act fully consumed before next pair
    xv0 = xva; yv0 = yva; xv1 = xvb; yv1 = yvb;
  }
}

// tensor_dense + mono/dipo outputs, 2 nodes per 256-thread block; within a
// node: lt = r*32+f. Barrier-free path loop with 5-step shfl_xor reductions
// (masks <=16 stay inside each 32-lane r-group).
__global__ void final_kernel(const float* __restrict__ xb, const float* __restrict__ tdW,
                             const float* __restrict__ monoW, const float* __restrict__ ebias,
                             const int* __restrict__ Z, float* __restrict__ out) {
  __shared__ float xl[2][288];
  __shared__ float cb[2][16];
  const int tid = threadIdx.x;
  const int ni = tid >> 7;          // node half 0/1
  const int lt = tid & 127;
  const int r = lt >> 5, f = lt & 31;
  const int n = blockIdx.x * 2 + ni;
  for (int i = lt; i < 288; i += 128) xl[ni][i] = xb[n * 288 + i];
  __syncthreads();
  float creg = 0.0f;  // c[r][g=f] accumulator, valid on f<4 threads
  #pragma unroll
  for (int t = 0; t < 7; ++t) {
    const int l1 = tL1[t], l2 = tL2[t], l3 = tL3[t];
    const bool active = (l3 == 0) ? (r == 0) : (r >= 1);   // uniform per 32-lane group
    float b = 0.0f;
    if (active) {
      #pragma unroll
      for (int i = 0; i < kWID[l1]; ++i) {
        const int p = kOFF[l1] + i;
        float xp = xl[ni][p * 32 + f];
        #pragma unroll
        for (int j = 0; j < kWID[l2]; ++j) {
          const int q = kOFF[l2] + j;
          b += GAUNT_d[(p * 9 + q) * 9 + r] * xp * xl[ni][q * 32 + f];
        }
      }
    }
    const float* w = tdW + ((l1 * 3 + l2) * 2 + l3) * 128;
    const float4 wv = *(const float4*)&w[f * 4];
    float p0 = b * wv.x, p1 = b * wv.y, p2 = b * wv.z, p3 = b * wv.w;
    #pragma unroll
    for (int m = 1; m <= 16; m <<= 1) {   // masks <=16 stay within the 32-lane group
      p0 += __shfl_xor(p0, m, 64);
      p1 += __shfl_xor(p1, m, 64);
      p2 += __shfl_xor(p2, m, 64);
      p3 += __shfl_xor(p3, m, 64);
    }
    if (active) {
      if (f == 0) creg += p0;
      else if (f == 1) creg += p1;
      else if (f == 2) creg += p2;
      else if (f == 3) creg += p3;
    }
  }
  if (f < 4) cb[ni][r * 4 + f] = creg;
  __syncthreads();
  if (lt < 4) {
    int g = lt;
    float m = 0.0f;
    #pragma unroll
    for (int j = 0; j < 4; ++j) m += cb[ni][j] * monoW[j * 4 + g];
    out[n * 4 + g] = m + ebias[Z[n]];
  }
  if (lt < 12) {
    int row = lt / 4 + 1, g = lt % 4;
    float s = cb[ni][g];
    float gate = (s > -1.0f && s < 1.0f) ? 1.0f : 0.0f;
    out[NN * 4 + n * 12 + (row - 1) * 4 + g] = cb[ni][row * 4 + g] * gate * 0.3f;
  }
}

extern "C" void kernel_launch(void* const* d_in, const int* in_sizes, int n_in,
                              void* d_out, int out_size, void* d_ws, size_t ws_size,
                              hipStream_t stream) {
  const float* positions = (const float*)d_in[0];
  const float* embed     = (const float*)d_in[1];
  const float* mpW       = (const float*)d_in[2];   // (3,3,3,3,8,32)
  const float* d1W       = (const float*)d_in[3];   // (3,3,32,32)
  const float* d1b       = (const float*)d_in[4];   // (3,32)
  const float* d2W       = (const float*)d_in[5];
  const float* d2b       = (const float*)d_in[6];
  const float* tdW       = (const float*)d_in[7];   // (3,3,2,32,4)
  const float* monoW     = (const float*)d_in[8];   // (4,4)
  const float* ebias     = (const float*)d_in[9];   // (18,)
  const int* Z   = (const int*)d_in[10];
  const int* dst = (const int*)d_in[11];
  const int* src = (const int*)d_in[12];
  float* out = (float*)d_out;

  float* Yb = (float*)d_ws;                 // NE*9  (dst-sorted)
  float* Rb = Yb + (size_t)NE * 9;          // NE*8  (dst-sorted)
  float* xb = Rb + (size_t)NE * 8;          // NN*288
  float* yb = xb + (size_t)NN * 288;        // NN*288
  // base footprint without Cb:
  size_t base_f = (size_t)NE * 9 + (size_t)NE * 8 + (size_t)NN * 288 * 2;
  size_t need_pc = (base_f + (size_t)NE * 116) * 4 + ((size_t)NE * 2 + NN) * 4;
  bool pc = ws_size >= need_pc;

  float* Cb = yb + (size_t)NN * 288;        // NE*116 (only if pc)
  float* after = pc ? (Cb + (size_t)NE * 116) : Cb;
  int* ssrc = (int*)after;                  // NE  (dst-sorted src ids)
  int* sdst = ssrc + NE;                    // NE  (sorted dst ids)
  int* wofs = sdst + NE;                    // NN  (hist counters -> scatter cursors)

  gaunt_kernel<<<1, 768, 0, stream>>>();
  hipMemsetAsync(wofs, 0, NN * sizeof(int), stream);
  hist_kernel<<<NE / 256, 256, 0, stream>>>(dst, wofs);
  scan_kernel<<<1, 1024, 0, stream>>>(wofs);
  edge_kernel<<<NE / 256, 256, 0, stream>>>(positions, src, dst, wofs, ssrc, sdst, Yb, Rb);
  if (pc) coef_kernel<<<NE / CEPB, 256, 0, stream>>>(Yb, Cb);
  init_kernel<<<(NN * 288 + 255) / 256, 256, 0, stream>>>(embed, Z, xb, yb);

  for (int it = 0; it < 3; ++it) {
    if (pc) {
      if (it == 0)
        message0_kernel<<<NE / M32, MT2, 0, stream>>>(xb, yb, Rb, Cb, mpW, ssrc, sdst);
      else
        message_kernel<<<NE / M32, MT2, 0, stream>>>(xb, yb, Rb, Cb, mpW + (size_t)it * 27 * 256, ssrc, sdst);
    } else {
      message_kernel_ic<<<NE / 8, 256, 0, stream>>>(xb, yb, Yb, Rb, mpW + (size_t)it * 27 * 256, ssrc, sdst);
    }
    dense_kernel<<<NN / DNB, 288, 0, stream>>>(yb, xb, d1W + (size_t)it * 3 * 1024, d1b + it * 32,
                                               d2W + (size_t)it * 3 * 1024, d2b + it * 32);
  }
  final_kernel<<<NN / 2, 256, 0, stream>>>(xb, tdW, monoW, ebias, Z, out);
}

// Round 19
// 372.943 us; speedup vs baseline: 1.1317x; 1.1317x over previous
//
#include <hip/hip_runtime.h>
#include <math.h>

#define NN 10000
#define NE 160000
#define MEPB 16          // edges per message block (16 thr/edge, 2 feats/thr)
#define MT 256           // message block threads
#define CEPB 16          // edges per coef block
#define DNB 4            // nodes per dense block (processed as pairs)

typedef float float2v __attribute__((ext_vector_type(2)));

namespace {
// MP_PATHS in reference order
constexpr int kL1[11] = {0,0,0,1,1,1,1,2,2,2,2};
constexpr int kL2[11] = {0,1,2,0,1,1,2,0,1,2,2};
constexpr int kL3[11] = {0,1,2,1,0,2,1,2,1,0,2};
// ((l1*3+l2)*3+l3) per path (W slab index)
constexpr int kWOFF[11] = {0,5,7,10,12,14,16,20,22,24,26};
// TD_PATHS in reference order
constexpr int tL1[7] = {0,0,1,1,1,2,2};
constexpr int tL2[7] = {0,1,0,1,2,1,2};
constexpr int tL3[7] = {0,1,1,0,1,1,0};
constexpr int kOFF[3] = {0,1,4};
constexpr int kWID[3] = {1,3,5};

// compile-time (t,i) -> tv-slot tables and c -> (r, tv-slot) tables (fallback kernel)
struct TVT { unsigned char t[35], p[35]; };
constexpr TVT makeTV() {
  TVT v{};
  int ti = 0;
  for (int t = 0; t < 11; ++t)
    for (int i = 0; i < kWID[kL1[t]]; ++i) {
      v.t[ti] = (unsigned char)t;
      v.p[ti] = (unsigned char)(kOFF[kL1[t]] + i);
      ++ti;
    }
  return v;
}
constexpr TVT TV = makeTV();

struct CTb { unsigned char r[116], tv[116]; };
constexpr CTb makeCT() {
  CTb v{};
  int c = 0, ti = 0;
  for (int t = 0; t < 11; ++t)
    for (int i = 0; i < kWID[kL1[t]]; ++i) {
      for (int k = 0; k < kWID[kL3[t]]; ++k) {
        v.r[c]  = (unsigned char)(kOFF[kL3[t]] + k);
        v.tv[c] = (unsigned char)ti;
        ++c;
      }
      ++ti;
    }
  v.r[115] = 0; v.tv[115] = 0;
  return v;
}
constexpr CTb CTC = makeCT();
}

__device__ float GAUNT_d[729];
__device__ unsigned char CT_P_d[115], CT_R_d[115], CT_L2_d[115];

// float32 spherical harmonics component (matches reference _sph_harm numerics)
__device__ __forceinline__ float sphf(int c, float x, float y, float z) {
  const float s3 = 1.7320508075688772f;
  switch (c) {
    case 0: return 1.0f;
    case 1: return x;
    case 2: return y;
    case 3: return z;
    case 4: return s3 * x * y;
    case 5: return s3 * y * z;
    case 6: return 0.5f * (3.0f * z * z - 1.0f);
    case 7: return s3 * x * z;
    default: return 0.5f * s3 * (x * x - y * y);
  }
}

// Gaunt table build: 16 double-trig calls total (staged in LDS), then a
// shared 128pt x 9comp Y table, then 729 threads do pure FMA loops.
__global__ void gaunt_kernel() {
  __shared__ float Ysh[128][9];
  __shared__ double cph[16], sph[16];
  __shared__ double stq[8], tsh[8], wsh[8];
  const int idx = threadIdx.x;
  const double T[8] = {-0.9602898564975363, -0.7966664774136267, -0.5255324099163290, -0.1834346424956498,
                        0.1834346424956498,  0.5255324099163290,  0.7966664774136267,  0.9602898564975363};
  const double Wq[8] = {0.1012285362903763, 0.2223810344533745, 0.3137066458778873, 0.3626837833783620,
                        0.3626837833783620, 0.3137066458778873, 0.2223810344533745, 0.1012285362903763};
  if (idx < 16) {
    double phi = (double)idx * (6.283185307179586 / 16.0);
    cph[idx] = cos(phi);
    sph[idx] = sin(phi);
  }
  if (idx < 8) {
    tsh[idx] = T[idx];
    wsh[idx] = Wq[idx] / 32.0;
    stq[idx] = sqrt(1.0 - T[idx] * T[idx]);
  }
  __syncthreads();
  for (int i = idx; i < 128 * 9; i += 768) {
    int k = i / 9, c = i - k * 9;
    int it = k >> 4, ip = k & 15;
    float xf = (float)(stq[it] * cph[ip]);
    float yf = (float)(stq[it] * sph[ip]);
    float zf = (float)tsh[it];
    Ysh[k][c] = sphf(c, xf, yf, zf);
  }
  __syncthreads();
  if (idx < 729) {
    int p = idx / 81, q = (idx / 9) % 9, r = idx % 9;
    double acc = 0.0;
    for (int k = 0; k < 128; ++k)  // same summation order as reference (it outer, ip inner)
      acc += wsh[k >> 4] * (double)Ysh[k][p] * (double)Ysh[k][q] * (double)Ysh[k][r];
    GAUNT_d[idx] = (fabs(acc) < 1e-10) ? 0.0f : (float)acc;
  }
  if (idx == 0) {
    // coef index -> (p_global, r_global, l2) tables, in (path, i, k) nesting order
    int c = 0;
    for (int t = 0; t < 11; ++t) {
      int l1 = kL1[t], l2 = kL2[t], l3 = kL3[t];
      for (int i = 0; i < kWID[l1]; ++i)
        for (int k = 0; k < kWID[l3]; ++k) {
          CT_P_d[c]  = (unsigned char)(kOFF[l1] + i);
          CT_R_d[c]  = (unsigned char)(kOFF[l3] + k);
          CT_L2_d[c] = (unsigned char)l2;
          ++c;
        }
    }
  }
}

// ---- destination-sorted edge order build ----
__global__ void hist_kernel(const int* __restrict__ dstI, int* __restrict__ cnt) {
  int e = blockIdx.x * 256 + threadIdx.x;
  if (e < NE) atomicAdd(&cnt[dstI[e]], 1);
}

// single-block in-place exclusive scan over wofs (counts -> start offsets)
__global__ void scan_kernel(int* __restrict__ wofs) {
  __shared__ int partial[1024];
  const int tid = threadIdx.x;           // 1024 threads, 10 elements each
  const int base = tid * 10;
  int local[10];
  int s = 0;
  #pragma unroll
  for (int i = 0; i < 10; ++i) {
    int idx = base + i;
    int v = (idx < NN) ? wofs[idx] : 0;
    local[i] = s;                        // exclusive within chunk
    s += v;
  }
  partial[tid] = s;
  __syncthreads();
  for (int off = 1; off < 1024; off <<= 1) {
    int v = (tid >= off) ? partial[tid - off] : 0;
    __syncthreads();
    partial[tid] += v;
    __syncthreads();
  }
  int pre = (tid == 0) ? 0 : partial[tid - 1];
  #pragma unroll
  for (int i = 0; i < 10; ++i) {
    int idx = base + i;
    if (idx < NN) wofs[idx] = pre + local[i];
  }
}

// edge basis, scattered directly into dst-sorted slot order
__global__ void edge_kernel(const float* __restrict__ pos,
                            const int* __restrict__ srcI, const int* __restrict__ dstI,
                            int* __restrict__ wofs, int* __restrict__ ssrc, int* __restrict__ sdst,
                            float* __restrict__ Yb, float* __restrict__ Rb) {
  int e = blockIdx.x * 256 + threadIdx.x;
  if (e >= NE) return;
  int s = srcI[e], d = dstI[e];
  float dx = pos[s * 3 + 0] - pos[d * 3 + 0];
  float dy = pos[s * 3 + 1] - pos[d * 3 + 1];
  float dz = pos[s * 3 + 2] - pos[d * 3 + 2];
  float r2 = dx * dx + dy * dy + dz * dz;
  float r = sqrtf(fmaxf(r2, 1e-12f));
  float inv = 1.0f / r;
  float x = dx * inv, y = dy * inv, z = dz * inv;
  const float s3 = 1.7320508075688772f;
  int sp = atomicAdd(&wofs[d], 1);       // dst-sorted slot
  ssrc[sp] = s;
  sdst[sp] = d;
  Yb[sp * 9 + 0] = 1.0f;
  Yb[sp * 9 + 1] = x;
  Yb[sp * 9 + 2] = y;
  Yb[sp * 9 + 3] = z;
  Yb[sp * 9 + 4] = s3 * x * y;
  Yb[sp * 9 + 5] = s3 * y * z;
  Yb[sp * 9 + 6] = 0.5f * (3.0f * z * z - 1.0f);
  Yb[sp * 9 + 7] = s3 * x * z;
  Yb[sp * 9 + 8] = 0.5f * s3 * (x * x - y * y);
  float rc = fminf(r, 5.0f - 1e-6f);
  float cut = (r < 5.0f) ? expf(-(rc * rc) / ((5.0f - rc) * (5.0f + rc))) : 0.0f;
  float yv = 1.0f / (1.0f + r);
  float om = 1.0f - yv;
  const float binom[8] = {1.f, 7.f, 21.f, 35.f, 35.f, 21.f, 7.f, 1.f};
  float yk[8], ok[8];
  yk[0] = 1.0f; ok[0] = 1.0f;
  #pragma unroll
  for (int k = 1; k < 8; ++k) { yk[k] = yk[k - 1] * yv; ok[k] = ok[k - 1] * om; }
  #pragma unroll
  for (int k = 0; k < 8; ++k) Rb[sp * 8 + k] = binom[k] * yk[k] * ok[7 - k] * cut;
}

// per-edge Gaunt-contracted coefficients, computed ONCE (iteration-independent):
// Cb[e][c] = sum_q G[p(c), q, r(c)] * Y[e][q], padded to 116 floats/row
__global__ void coef_kernel(const float* __restrict__ Yb, float* __restrict__ Cb) {
  __shared__ float Gs[729];
  __shared__ float Ys[CEPB][9];
  __shared__ unsigned char Tp[115], Tr[115], Tl2[115];
  const int tid = threadIdx.x;
  const int e0 = blockIdx.x * CEPB;
  for (int i = tid; i < 729; i += 256) Gs[i] = GAUNT_d[i];
  for (int i = tid; i < 115; i += 256) { Tp[i] = CT_P_d[i]; Tr[i] = CT_R_d[i]; Tl2[i] = CT_L2_d[i]; }
  for (int i = tid; i < CEPB * 9; i += 256) Ys[i / 9][i % 9] = Yb[e0 * 9 + i];
  __syncthreads();
  for (int i = tid; i < CEPB * 128; i += 256) {
    int ce = i >> 7, c = i & 127;
    if (c < 116) {
      float a = 0.0f;
      if (c < 115) {
        int p = Tp[c], r = Tr[c], l2 = Tl2[c];
        int q0 = (l2 == 0) ? 0 : ((l2 == 1) ? 1 : 4);
        int nq = (l2 == 0) ? 1 : ((l2 == 1) ? 3 : 5);
        for (int j = 0; j < nq; ++j) a += Gs[(p * 9 + q0 + j) * 9 + r] * Ys[ce][q0 + j];
      }
      Cb[(size_t)(e0 + ce) * 116 + c] = a;
    }
  }
}

// x init + y zero
__global__ void init_kernel(const float* __restrict__ embed, const int* __restrict__ Z,
                            float* __restrict__ xb, float* __restrict__ yb) {
  int idx = blockIdx.x * 256 + threadIdx.x;
  if (idx >= NN * 288) return;
  int n = idx / 288;
  int rem = idx - n * 288;
  int p = rem >> 5, f = rem & 31;
  xb[idx] = (p == 0) ? embed[Z[n] * 32 + f] : 0.0f;
  yb[idx] = 0.0f;
}

// edge-major message pass, packed-FP32 form: 16 threads/edge x 2 features/thread
// (ext_vector float2 -> v_pk_fma_f32), 16 edges/block. Ws/Ms share one LDS
// array; Ms reduction runs in two 8-edge sub-batches (seg-outer loop, no idiv).
__launch_bounds__(MT, 8)
__global__ void message_kernel(const float* __restrict__ xb, float* __restrict__ yb,
                               const float* __restrict__ Rb, const float* __restrict__ Cb,
                               const float* __restrict__ Wg,
                               const int* __restrict__ ssrc, const int* __restrict__ sdst) {
  __shared__ __align__(16) float U[11 * 256];    // phase A: Ws[t][k*32+f]; phase B: Ms[8][288]
  __shared__ __align__(16) float Cs[MEPB][116];
  __shared__ __align__(16) float Rs[MEPB][8];
  __shared__ int Ds[MEPB];
  __shared__ int Hs[2][9];
  __shared__ int nsegS[2];
  const int tid = threadIdx.x;
  const int e0 = blockIdx.x * MEPB;
  const int le = tid >> 4;          // edge slot 0..15
  const int f  = (tid & 15) * 2;    // even feature index; thread owns f, f+1

  // issue the x[src] gather FIRST (no LDS dependency); latency hides under staging
  const int sn = ssrc[e0 + le];
  float2v xs2[9];
  #pragma unroll
  for (int p = 0; p < 9; ++p) xs2[p] = *(const float2v*)&xb[sn * 288 + p * 32 + f];

  float* Ws = U;
  #pragma unroll
  for (int t = 0; t < 11; ++t) {
    const int off = kWOFF[t] * 256;
    Ws[t * 256 + tid] = Wg[off + tid];
  }
  {
    const float4* Cbv = (const float4*)Cb;
    float4* Csv = (float4*)Cs;
    #pragma unroll
    for (int i = tid; i < MEPB * 29; i += MT) Csv[i] = Cbv[(size_t)e0 * 29 + i];
  }
  for (int i = tid; i < MEPB * 8; i += MT) Rs[i >> 3][i & 7] = Rb[e0 * 8 + i];
  if (tid < MEPB) Ds[tid] = sdst[e0 + tid];
  __syncthreads();

  if (tid == 0) {
    // segment heads among the sorted edges, per 8-edge sub-batch
    #pragma unroll
    for (int b = 0; b < 2; ++b) {
      int ns = 0;
      #pragma unroll
      for (int i = 0; i < 8; ++i) {
        int gi = b * 8 + i;
        if (i == 0 || Ds[gi] != Ds[gi - 1]) Hs[b][ns++] = i;
      }
      Hs[b][ns] = 8;
      nsegS[b] = ns;
    }
  }

  // core math, packed over (f, f+1): per path t compute rw (8 pk-FMA), then
  // the (i,k) message terms; same summation order as the reference loop.
  float2v msg[9] = {{0.f,0.f},{0.f,0.f},{0.f,0.f},{0.f,0.f},{0.f,0.f},{0.f,0.f},{0.f,0.f},{0.f,0.f},{0.f,0.f}};
  int c = 0;
  #pragma unroll
  for (int t = 0; t < 11; ++t) {
    const float* base = &Ws[t * 256];
    float2v acc = {0.f, 0.f};
    #pragma unroll
    for (int k = 0; k < 8; ++k) {
      const float rv = Rs[le][k];
      const float2v rvv = {rv, rv};
      const float2v w2 = *(const float2v*)&base[k * 32 + f];
      acc = acc + rvv * w2;
    }
    const int o1 = kOFF[kL1[t]], w1 = kWID[kL1[t]];
    const int o3 = kOFF[kL3[t]], w3 = kWID[kL3[t]];
    #pragma unroll
    for (int i = 0; i < w1; ++i) {
      const float2v tvv = acc * xs2[o1 + i];
      #pragma unroll
      for (int k2 = 0; k2 < w3; ++k2) {
        const float cc = Cs[le][c]; ++c;
        const float2v ccv = {cc, cc};
        msg[o3 + k2] = msg[o3 + k2] + ccv * tvv;
      }
    }
  }

  // two sub-batch segmented reductions reusing U as Ms[8][288]
  float* Ms = U;
  #pragma unroll
  for (int b = 0; b < 2; ++b) {
    __syncthreads();                  // b=0: all Ws reads done; b=1: batch-0 reads done
    if ((le >> 3) == b) {
      #pragma unroll
      for (int rr = 0; rr < 9; ++rr)
        *(float2v*)&Ms[(le & 7) * 288 + rr * 32 + f] = msg[rr];
    }
    __syncthreads();
    const int ns = nsegS[b];
    for (int s = 0; s < ns; ++s) {    // segment-outer loop: no integer division
      const int h = Hs[b][s], hend = Hs[b][s + 1];
      const int dbase = Ds[b * 8 + h] * 288;
      for (int rf = tid; rf < 288; rf += MT) {
        float a = 0.0f;
        for (int e = h; e < hend; ++e) a += Ms[e * 288 + rf];
        atomicAdd(&yb[dbase + rf], a);
      }
    }
  }
}

// iteration-0 message pass: x is zero except the p=0 (embedding) row, so only
// the 3 MP paths with l1=0 contribute (exact zeros elsewhere). 1 x-row gather,
// 3 W slabs, 9 C coefficients; reduction phase identical to message_kernel.
__launch_bounds__(MT, 8)
__global__ void message0_kernel(const float* __restrict__ xb, float* __restrict__ yb,
                                const float* __restrict__ Rb, const float* __restrict__ Cb,
                                const float* __restrict__ Wg,
                                const int* __restrict__ ssrc, const int* __restrict__ sdst) {
  __shared__ __align__(16) float U[8 * 288];     // phase A: Ws[3][256] (first 768); phase B: Ms[8][288]
  __shared__ __align__(16) float Cs[MEPB][12];
  __shared__ __align__(16) float Rs[MEPB][8];
  __shared__ int Ds[MEPB];
  __shared__ int Hs[2][9];
  __shared__ int nsegS[2];
  const int tid = threadIdx.x;
  const int e0 = blockIdx.x * MEPB;
  const int le = tid >> 4;          // edge slot 0..15
  const int f  = (tid & 15) * 2;    // even feature index; thread owns f, f+1

  const int sn = ssrc[e0 + le];
  const float2v xs0 = *(const float2v*)&xb[sn * 288 + f];   // p=0 row only

  float* Ws = U;
  #pragma unroll
  for (int t = 0; t < 3; ++t) {
    const int off = kWOFF[t] * 256;   // kWOFF[0..2] = 0,5,7
    Ws[t * 256 + tid] = Wg[off + tid];
  }
  if (tid < MEPB * 3) {               // 48 float4: first 12 coefs of each edge row
    const float4* Cbv = (const float4*)Cb;
    int row = tid / 3, c4 = tid - row * 3;
    ((float4*)Cs)[row * 3 + c4] = Cbv[(size_t)(e0 + row) * 29 + c4];
  }
  for (int i = tid; i < MEPB * 8; i += MT) Rs[i >> 3][i & 7] = Rb[e0 * 8 + i];
  if (tid < MEPB) Ds[tid] = sdst[e0 + tid];
  __syncthreads();

  if (tid == 0) {
    #pragma unroll
    for (int b = 0; b < 2; ++b) {
      int ns = 0;
      #pragma unroll
      for (int i = 0; i < 8; ++i) {
        int gi = b * 8 + i;
        if (i == 0 || Ds[gi] != Ds[gi - 1]) Hs[b][ns++] = i;
      }
      Hs[b][ns] = 8;
      nsegS[b] = ns;
    }
  }

  // rw for the 3 surviving paths, then the 9 message terms
  float2v msg[9];
  {
    float2v acc[3];
    #pragma unroll
    for (int t = 0; t < 3; ++t) {
      const float* base = &Ws[t * 256];
      float2v a = {0.f, 0.f};
      #pragma unroll
      for (int k = 0; k < 8; ++k) {
        const float rv = Rs[le][k];
        const float2v rvv = {rv, rv};
        const float2v w2 = *(const float2v*)&base[k * 32 + f];
        a = a + rvv * w2;
      }
      acc[t] = a;
    }
    const float2v tv0 = acc[0] * xs0;   // path (0,0,0) -> r=0,   c=0
    const float2v tv1 = acc[1] * xs0;   // path (0,1,1) -> r=1..3, c=1..3
    const float2v tv2 = acc[2] * xs0;   // path (0,2,2) -> r=4..8, c=4..8
    msg[0] = (float2v){Cs[le][0], Cs[le][0]} * tv0;
    #pragma unroll
    for (int k = 0; k < 3; ++k) {
      const float cc = Cs[le][1 + k];
      msg[1 + k] = (float2v){cc, cc} * tv1;
    }
    #pragma unroll
    for (int k = 0; k < 5; ++k) {
      const float cc = Cs[le][4 + k];
      msg[4 + k] = (float2v){cc, cc} * tv2;
    }
  }

  // two sub-batch segmented reductions reusing U as Ms[8][288]
  float* Ms = U;
  #pragma unroll
  for (int b = 0; b < 2; ++b) {
    __syncthreads();                  // b=0: all Ws reads done; b=1: batch-0 reads done
    if ((le >> 3) == b) {
      #pragma unroll
      for (int rr = 0; rr < 9; ++rr)
        *(float2v*)&Ms[(le & 7) * 288 + rr * 32 + f] = msg[rr];
    }
    __syncthreads();
    const int ns = nsegS[b];
    for (int s = 0; s < ns; ++s) {
      const int h = Hs[b][s], hend = Hs[b][s + 1];
      const int dbase = Ds[b * 8 + h] * 288;
      for (int rf = tid; rf < 288; rf += MT) {
        float a = 0.0f;
        for (int e = h; e < hend; ++e) a += Ms[e * 288 + rf];
        atomicAdd(&yb[dbase + rf], a);
      }
    }
  }
}

// fallback (in-kernel coef, round-3 form, 8 edges/block) if workspace too small for Cb
__launch_bounds__(256)
__global__ void message_kernel_ic(const float* __restrict__ xb, float* __restrict__ yb,
                                  const float* __restrict__ Yb, const float* __restrict__ Rb,
                                  const float* __restrict__ Wg,
                                  const int* __restrict__ ssrc, const int* __restrict__ sdst) {
  __shared__ float Gs[729];
  __shared__ float Ws[11 * 256];
  __shared__ float Ys[8][9];
  __shared__ float Rs[8][8];
  __shared__ float Cs[8][116];
  __shared__ float Ms[8][288];
  __shared__ int Ds[8];
  __shared__ int Hs[9];
  __shared__ int nseg_s;
  __shared__ unsigned char Tp[115], Tr[115], Tl2[115];
  const int tid = threadIdx.x;
  const int e0 = blockIdx.x * 8;

  for (int i = tid; i < 729; i += 256) Gs[i] = GAUNT_d[i];
  for (int i = tid; i < 115; i += 256) { Tp[i] = CT_P_d[i]; Tr[i] = CT_R_d[i]; Tl2[i] = CT_L2_d[i]; }
  #pragma unroll
  for (int t = 0; t < 11; ++t) Ws[t * 256 + tid] = Wg[kWOFF[t] * 256 + tid];
  for (int i = tid; i < 8 * 16; i += 256) {
    int le = i >> 4, q = i & 15;
    if (q < 9) Ys[le][q] = Yb[(e0 + le) * 9 + q];
  }
  for (int i = tid; i < 8 * 8; i += 256) Rs[i >> 3][i & 7] = Rb[e0 * 8 + i];
  if (tid < 8) Ds[tid] = sdst[e0 + tid];
  __syncthreads();

  const int le = tid >> 5, f = tid & 31;
  const int sn = ssrc[e0 + le];
  float xs[9];
  #pragma unroll
  for (int p = 0; p < 9; ++p) xs[p] = xb[sn * 288 + p * 32 + f];

  for (int i = tid; i < 8 * 128; i += 256) {
    int ce = i >> 7, c = i & 127;
    if (c < 115) {
      int p = Tp[c], r = Tr[c], l2 = Tl2[c];
      int q0 = (l2 == 0) ? 0 : ((l2 == 1) ? 1 : 4);
      int nq = (l2 == 0) ? 1 : ((l2 == 1) ? 3 : 5);
      float a = 0.0f;
      for (int j = 0; j < nq; ++j) a += Gs[(p * 9 + q0 + j) * 9 + r] * Ys[ce][q0 + j];
      Cs[ce][c] = a;
    }
  }
  if (tid == 0) {
    int ns = 0;
    #pragma unroll
    for (int i = 0; i < 8; ++i)
      if (i == 0 || Ds[i] != Ds[i - 1]) Hs[ns++] = i;
    Hs[ns] = 8;
    nseg_s = ns;
  }
  __syncthreads();

  const float4 R0 = *(const float4*)&Rs[le][0];
  const float4 R1 = *(const float4*)&Rs[le][4];
  float rw[11];
  #pragma unroll
  for (int t = 0; t < 11; ++t) {
    const float* base = &Ws[t * 256];
    rw[t] = R0.x * base[f] + R0.y * base[32 + f] + R0.z * base[64 + f] + R0.w * base[96 + f]
          + R1.x * base[128 + f] + R1.y * base[160 + f] + R1.z * base[192 + f] + R1.w * base[224 + f];
  }
  float tv[35];
  #pragma unroll
  for (int j = 0; j < 35; ++j) tv[j] = rw[TV.t[j]] * xs[TV.p[j]];
  float msg[9] = {0.f, 0.f, 0.f, 0.f, 0.f, 0.f, 0.f, 0.f, 0.f};
  #pragma unroll
  for (int c = 0; c < 115; ++c) msg[CTC.r[c]] += Cs[le][c] * tv[CTC.tv[c]];
  #pragma unroll
  for (int rr = 0; rr < 9; ++rr) Ms[le][rr * 32 + f] = msg[rr];
  __syncthreads();

  const int nseg = nseg_s;
  for (int i = tid; i < nseg * 288; i += 256) {
    int s = i / 288, rf = i - s * 288;
    int h = Hs[s], hend = Hs[s + 1];
    float a = 0.0f;
    for (int e = h; e < hend; ++e) a += Ms[e][rf];
    atomicAdd(&yb[Ds[h] * 288 + rf], a);
  }
}

// fused dense1 + silu_e3 + dense2 + residual; DNB nodes per block as pairs.
// W read straight from global: W1/W2 are identical for all blocks, so one L1
// copy per CU serves every resident block.
__launch_bounds__(288)
__global__ void dense_kernel(float* __restrict__ ybuf, float* __restrict__ xb,
                             const float* __restrict__ W1, const float* __restrict__ b1,
                             const float* __restrict__ W2, const float* __restrict__ b2) {
  __shared__ float yn0[288], yn1[288];
  __shared__ float act0[288], act1[288];
  __shared__ float sb0[32], sb1[32];
  const int tid = threadIdx.x;  // p*32+g
  const int p = tid >> 5, g = tid & 31;
  const int dg = (p == 0) ? 0 : ((p < 4) ? 1 : 2);
  const float b1v = b1[g], b2v = b2[g];
  const float* W1d = W1 + dg * 1024 + g;   // W1[(dg*32+f)*32+g] = W1d[f*32]
  const float* W2d = W2 + dg * 1024 + g;
  const int n0 = blockIdx.x * DNB;
  float xv0 = xb[n0 * 288 + tid];
  float yv0 = ybuf[n0 * 288 + tid];
  float xv1 = xb[(n0 + 1) * 288 + tid];
  float yv1 = ybuf[(n0 + 1) * 288 + tid];
  for (int n = n0; n < n0 + DNB; n += 2) {
    yn0[tid] = xv0 + yv0;
    yn1[tid] = xv1 + yv1;
    ybuf[n * 288 + tid] = 0.0f;        // zero for next iteration's atomics
    ybuf[(n + 1) * 288 + tid] = 0.0f;
    __syncthreads();
    float xva = 0.0f, yva = 0.0f, xvb = 0.0f, yvb = 0.0f;
    if (n + 2 < n0 + DNB) {            // prefetch next pair under compute
      xva = xb[(n + 2) * 288 + tid];
      yva = ybuf[(n + 2) * 288 + tid];
      xvb = xb[(n + 3) * 288 + tid];
      yvb = ybuf[(n + 3) * 288 + tid];
    }
    float a0 = (p == 0) ? b1v : 0.0f;
    float a1 = (p == 0) ? b1v : 0.0f;
    #pragma unroll
    for (int f = 0; f < 32; ++f) {
      const float w = W1d[f * 32];
      a0 += yn0[p * 32 + f] * w;
      a1 += yn1[p * 32 + f] * w;
    }
    if (p == 0) { sb0[g] = a0; sb1[g] = a1; }
    __syncthreads();
    const float s0 = sb0[g], s1 = sb1[g];
    const float sg0 = 1.0f / (1.0f + expf(-s0));
    const float sg1 = 1.0f / (1.0f + expf(-s1));
    const float v0 = (p == 0) ? s0 * sg0 : a0 * (sg0 * (1.0f + s0 * (1.0f - sg0)));
    const float v1 = (p == 0) ? s1 * sg1 : a1 * (sg1 * (1.0f + s1 * (1.0f - sg1)));
    act0[tid] = v0;
    act1[tid] = v1;
    __syncthreads();
    float o0 = (p == 0) ? b2v : 0.0f;
    float o1 = (p == 0) ? b2v : 0.0f;
    #pragma unroll
    for (int f = 0; f < 32; ++f) {
      const float w = W2d[f * 32];
      o0 += act0[p * 32 + f] * w;
      o1 += act1[p * 32 + f] * w;
    }
    xb[n * 288 + tid] = xv0 + o0;
    xb[(n + 1) * 288 + tid] = xv1 + o1;
    __syncthreads();                   // yn/act fully consumed before next pair
    xv0 = xva; yv0 = yva; xv1 = xvb; yv1 = yvb;
  }
}

// tensor_dense + mono/dipo outputs, 2 nodes per 256-thread block; within a
// node: lt = r*32+f. Barrier-free path loop with 5-step shfl_xor reductions
// (masks <=16 stay inside each 32-lane r-group).
__global__ void final_kernel(const float* __restrict__ xb, const float* __restrict__ tdW,
                             const float* __restrict__ monoW, const float* __restrict__ ebias,
                             const int* __restrict__ Z, float* __restrict__ out) {
  __shared__ float xl[2][288];
  __shared__ float cb[2][16];
  const int tid = threadIdx.x;
  const int ni = tid >> 7;          // node half 0/1
  const int lt = tid & 127;
  const int r = lt >> 5, f = lt & 31;
  const int n = blockIdx.x * 2 + ni;
  for (int i = lt; i < 288; i += 128) xl[ni][i] = xb[n * 288 + i];
  __syncthreads();
  float creg = 0.0f;  // c[r][g=f] accumulator, valid on f<4 threads
  #pragma unroll
  for (int t = 0; t < 7; ++t) {
    const int l1 = tL1[t], l2 = tL2[t], l3 = tL3[t];
    const bool active = (l3 == 0) ? (r == 0) : (r >= 1);   // uniform per 32-lane group
    float b = 0.0f;
    if (active) {
      #pragma unroll
      for (int i = 0; i < kWID[l1]; ++i) {
        const int p = kOFF[l1] + i;
        float xp = xl[ni][p * 32 + f];
        #pragma unroll
        for (int j = 0; j < kWID[l2]; ++j) {
          const int q = kOFF[l2] + j;
          b += GAUNT_d[(p * 9 + q) * 9 + r] * xp * xl[ni][q * 32 + f];
        }
      }
    }
    const float* w = tdW + ((l1 * 3 + l2) * 2 + l3) * 128;
    const float4 wv = *(const float4*)&w[f * 4];
    float p0 = b * wv.x, p1 = b * wv.y, p2 = b * wv.z, p3 = b * wv.w;
    #pragma unroll
    for (int m = 1; m <= 16; m <<= 1) {   // masks <=16 stay within the 32-lane group
      p0 += __shfl_xor(p0, m, 64);
      p1 += __shfl_xor(p1, m, 64);
      p2 += __shfl_xor(p2, m, 64);
      p3 += __shfl_xor(p3, m, 64);
    }
    if (active) {
      if (f == 0) creg += p0;
      else if (f == 1) creg += p1;
      else if (f == 2) creg += p2;
      else if (f == 3) creg += p3;
    }
  }
  if (f < 4) cb[ni][r * 4 + f] = creg;
  __syncthreads();
  if (lt < 4) {
    int g = lt;
    float m = 0.0f;
    #pragma unroll
    for (int j = 0; j < 4; ++j) m += cb[ni][j] * monoW[j * 4 + g];
    out[n * 4 + g] = m + ebias[Z[n]];
  }
  if (lt < 12) {
    int row = lt / 4 + 1, g = lt % 4;
    float s = cb[ni][g];
    float gate = (s > -1.0f && s < 1.0f) ? 1.0f : 0.0f;
    out[NN * 4 + n * 12 + (row - 1) * 4 + g] = cb[ni][row * 4 + g] * gate * 0.3f;
  }
}

extern "C" void kernel_launch(void* const* d_in, const int* in_sizes, int n_in,
                              void* d_out, int out_size, void* d_ws, size_t ws_size,
                              hipStream_t stream) {
  const float* positions = (const float*)d_in[0];
  const float* embed     = (const float*)d_in[1];
  const float* mpW       = (const float*)d_in[2];   // (3,3,3,3,8,32)
  const float* d1W       = (const float*)d_in[3];   // (3,3,32,32)
  const float* d1b       = (const float*)d_in[4];   // (3,32)
  const float* d2W       = (const float*)d_in[5];
  const float* d2b       = (const float*)d_in[6];
  const float* tdW       = (const float*)d_in[7];   // (3,3,2,32,4)
  const float* monoW     = (const float*)d_in[8];   // (4,4)
  const float* ebias     = (const float*)d_in[9];   // (18,)
  const int* Z   = (const int*)d_in[10];
  const int* dst = (const int*)d_in[11];
  const int* src = (const int*)d_in[12];
  float* out = (float*)d_out;

  float* Yb = (float*)d_ws;                 // NE*9  (dst-sorted)
  float* Rb = Yb + (size_t)NE * 9;          // NE*8  (dst-sorted)
  float* xb = Rb + (size_t)NE * 8;          // NN*288
  float* yb = xb + (size_t)NN * 288;        // NN*288
  // base footprint without Cb:
  size_t base_f = (size_t)NE * 9 + (size_t)NE * 8 + (size_t)NN * 288 * 2;
  size_t need_pc = (base_f + (size_t)NE * 116) * 4 + ((size_t)NE * 2 + NN) * 4;
  bool pc = ws_size >= need_pc;

  float* Cb = yb + (size_t)NN * 288;        // NE*116 (only if pc)
  float* after = pc ? (Cb + (size_t)NE * 116) : Cb;
  int* ssrc = (int*)after;                  // NE  (dst-sorted src ids)
  int* sdst = ssrc + NE;                    // NE  (sorted dst ids)
  int* wofs = sdst + NE;                    // NN  (hist counters -> scatter cursors)

  gaunt_kernel<<<1, 768, 0, stream>>>();
  hipMemsetAsync(wofs, 0, NN * sizeof(int), stream);
  hist_kernel<<<NE / 256, 256, 0, stream>>>(dst, wofs);
  scan_kernel<<<1, 1024, 0, stream>>>(wofs);
  edge_kernel<<<NE / 256, 256, 0, stream>>>(positions, src, dst, wofs, ssrc, sdst, Yb, Rb);
  if (pc) coef_kernel<<<NE / CEPB, 256, 0, stream>>>(Yb, Cb);
  init_kernel<<<(NN * 288 + 255) / 256, 256, 0, stream>>>(embed, Z, xb, yb);

  for (int it = 0; it < 3; ++it) {
    if (pc) {
      if (it == 0)
        message0_kernel<<<NE / MEPB, MT, 0, stream>>>(xb, yb, Rb, Cb, mpW, ssrc, sdst);
      else
        message_kernel<<<NE / MEPB, MT, 0, stream>>>(xb, yb, Rb, Cb, mpW + (size_t)it * 27 * 256, ssrc, sdst);
    } else {
      message_kernel_ic<<<NE / 8, 256, 0, stream>>>(xb, yb, Yb, Rb, mpW + (size_t)it * 27 * 256, ssrc, sdst);
    }
    dense_kernel<<<NN / DNB, 288, 0, stream>>>(yb, xb, d1W + (size_t)it * 3 * 1024, d1b + it * 32,
                                               d2W + (size_t)it * 3 * 1024, d2b + it * 32);
  }
  final_kernel<<<NN / 2, 256, 0, stream>>>(xb, tdW, monoW, ebias, Z, out);
}